// Round 2
// baseline (3764.338 us; speedup 1.0000x reference)
//
#include <hip/hip_runtime.h>
#include <hip/hip_bf16.h>

#define B_ 16
#define L_ 1024
#define D_ 512
#define K_ 64
#define NL_ 16
#define SMALL_ 8
#define SET_ 128

__device__ inline float waveSum(float v){
#pragma unroll
  for (int o=32;o>0;o>>=1) v += __shfl_down(v,o);
  return v;
}
__device__ inline float waveMax(float v){
#pragma unroll
  for (int o=32;o>0;o>>=1) v = fmaxf(v,__shfl_down(v,o));
  return v;
}

// ---- rate = relu(t_emb @ Wa^T + ba), 8 rows per block ----
__global__ __launch_bounds__(256) void k_rate(const float* __restrict__ temb, const float* __restrict__ Wa,
                                              const float* __restrict__ ba, float* __restrict__ att){
  int row0 = blockIdx.x*8;                 // global row in [0, B*L)
  __shared__ float rows[8][512];
  int tid = threadIdx.x;
  {
    const float4* src = reinterpret_cast<const float4*>(temb + (size_t)row0*512);
    float4* dst = reinterpret_cast<float4*>(&rows[0][0]);
#pragma unroll
    for (int i=0;i<4;i++) dst[tid + i*256] = src[tid + i*256];
  }
  __syncthreads();
  int wave = tid>>6, lane = tid&63;
  for (int h=0; h<16; ++h){
    int k = wave*16 + h;
    const float* wp = Wa + (size_t)k*512 + lane*8;
    float4 w0 = *reinterpret_cast<const float4*>(wp);
    float4 w1 = *reinterpret_cast<const float4*>(wp+4);
    float bav = ba[k];
#pragma unroll
    for (int r=0;r<8;++r){
      const float* rp = &rows[r][lane*8];
      float4 e0 = *reinterpret_cast<const float4*>(rp);
      float4 e1 = *reinterpret_cast<const float4*>(rp+4);
      float s = e0.x*w0.x + e0.y*w0.y + e0.z*w0.z + e0.w*w0.w
              + e1.x*w1.x + e1.y*w1.y + e1.z*w1.z + e1.w*w1.w;
      s = waveSum(s);
      if (lane==0) att[(size_t)(row0 + r)*64 + k] = fmaxf(s + bav, 0.0f);
    }
  }
}

// ---- softmax over sequence dim (axis L) per (b,k), in place on att[B,L,K] ----
__global__ __launch_bounds__(256) void k_softmax(float* __restrict__ att){
  int b = blockIdx.x >> 6, k = blockIdx.x & 63;
  float* base = att + (size_t)b*L_*K_ + k;
  int tid = threadIdx.x;
  float v[4];
  float mx = -1e30f;
#pragma unroll
  for (int i=0;i<4;i++){ v[i] = base[(size_t)(tid + i*256)*64]; mx = fmaxf(mx, v[i]); }
  __shared__ float red[8];
  int wave = tid>>6, lane = tid&63;
  float wm = waveMax(mx);
  if (lane==0) red[wave] = wm;
  __syncthreads();
  mx = fmaxf(fmaxf(red[0],red[1]),fmaxf(red[2],red[3]));
  float sum = 0.f;
#pragma unroll
  for (int i=0;i<4;i++){ v[i] = __expf(v[i]-mx); sum += v[i]; }
  float ws = waveSum(sum);
  if (lane==0) red[4+wave] = ws;
  __syncthreads();
  sum = red[4]+red[5]+red[6]+red[7];
  float inv = 1.0f/sum;
#pragma unroll
  for (int i=0;i<4;i++) base[(size_t)(tid + i*256)*64] = v[i]*inv;
}

// ---- s partials: spart[b][lc][k][d] = sum_{l in chunk} att[b,l,k]*temb[b,l,d] ----
__global__ __launch_bounds__(256) void k_spart(const float* __restrict__ temb, const float* __restrict__ att,
                                               float* __restrict__ spart){
  int b = blockIdx.x, dt = blockIdx.y, lc = blockIdx.z;
  __shared__ float se[8][128];
  __shared__ float sa[8][64];
  int tid = threadIdx.x;
  int r8 = tid>>5;            // 0..7
  int c32 = tid&31;           // 0..31
  float acc[8][4];
#pragma unroll
  for (int i=0;i<8;i++){
#pragma unroll
    for(int j=0;j<4;j++) acc[i][j]=0.f;
  }
  int kg = r8*8;
  int dg = c32*4;
  int lbase = lc*256;
  for (int l0=0; l0<256; l0+=8){
    int l = lbase + l0 + r8;
    *reinterpret_cast<float4*>(&se[r8][c32*4]) =
      *reinterpret_cast<const float4*>(&temb[((size_t)(b*L_ + l))*512 + dt*128 + c32*4]);
    *reinterpret_cast<float2*>(&sa[r8][c32*2]) =
      *reinterpret_cast<const float2*>(&att[((size_t)(b*L_ + l))*64 + c32*2]);
    __syncthreads();
#pragma unroll 1
    for (int i=0;i<8;i++){
      float4 e = *reinterpret_cast<const float4*>(&se[i][dg]);
      float4 A0 = *reinterpret_cast<const float4*>(&sa[i][kg]);
      float4 A1 = *reinterpret_cast<const float4*>(&sa[i][kg+4]);
      float a[8];
      a[0]=A0.x;a[1]=A0.y;a[2]=A0.z;a[3]=A0.w;a[4]=A1.x;a[5]=A1.y;a[6]=A1.z;a[7]=A1.w;
#pragma unroll
      for (int kk=0;kk<8;kk++){
        acc[kk][0] += a[kk]*e.x;
        acc[kk][1] += a[kk]*e.y;
        acc[kk][2] += a[kk]*e.z;
        acc[kk][3] += a[kk]*e.w;
      }
    }
    __syncthreads();
  }
#pragma unroll
  for (int kk=0;kk<8;kk++){
    float4 o; o.x=acc[kk][0];o.y=acc[kk][1];o.z=acc[kk][2];o.w=acc[kk][3];
    *reinterpret_cast<float4*>(&spart[((size_t)((b*4+lc)*64 + kg+kk))*512 + dt*128 + dg]) = o;
  }
}

// ---- reduce partials, scale, LN(ga,bea), vec = relu(s@Wp+bp) -> fiin[b][e*64+k] ----
__global__ __launch_bounds__(64) void k_sln_vec(const float* __restrict__ spart,
     const float* __restrict__ ga, const float* __restrict__ bea,
     const float* __restrict__ Wp, const float* __restrict__ bp,
     float* __restrict__ fiin){
  int bk = blockIdx.x; int b = bk>>6, k = bk&63;
  int lane = threadIdx.x;
  int d0 = lane*8;
  float sv[8];
#pragma unroll
  for (int j=0;j<8;j++) sv[j]=0.f;
#pragma unroll
  for (int lc=0;lc<4;lc++){
    const float* p = spart + ((size_t)((b*4+lc)*64 + k))*512 + d0;
    float4 x0 = *reinterpret_cast<const float4*>(p);
    float4 x1 = *reinterpret_cast<const float4*>(p+4);
    sv[0]+=x0.x; sv[1]+=x0.y; sv[2]+=x0.z; sv[3]+=x0.w;
    sv[4]+=x1.x; sv[5]+=x1.y; sv[6]+=x1.z; sv[7]+=x1.w;
  }
  const float inv_sqrt_L = 0.03125f;
  float s1=0.f, s2=0.f;
#pragma unroll
  for (int j=0;j<8;j++){ sv[j]*=inv_sqrt_L; s1+=sv[j]; s2+=sv[j]*sv[j]; }
#pragma unroll
  for (int o=32;o>0;o>>=1){ s1 += __shfl_xor(s1,o); s2 += __shfl_xor(s2,o); }
  float m = s1*(1.0f/512.0f);
  float var = s2*(1.0f/512.0f) - m*m;
  float rstd = rsqrtf(var + 1e-5f);
  const float* gap = ga + (size_t)k*512 + d0;
  const float* bep = bea + (size_t)k*512 + d0;
  float4 g0 = *reinterpret_cast<const float4*>(gap);
  float4 g1 = *reinterpret_cast<const float4*>(gap+4);
  float4 e0 = *reinterpret_cast<const float4*>(bep);
  float4 e1 = *reinterpret_cast<const float4*>(bep+4);
  float gav[8] = {g0.x,g0.y,g0.z,g0.w,g1.x,g1.y,g1.z,g1.w};
  float bev[8] = {e0.x,e0.y,e0.z,e0.w,e1.x,e1.y,e1.z,e1.w};
  float acc[8];
#pragma unroll
  for (int e=0;e<8;e++) acc[e]=0.f;
#pragma unroll
  for (int j=0;j<8;j++){
    float sl = (sv[j]-m)*rstd*gav[j] + bev[j];
    const float* wp = Wp + ((size_t)k*512 + d0 + j)*8;
    float4 w0 = *reinterpret_cast<const float4*>(wp);
    float4 w1 = *reinterpret_cast<const float4*>(wp+4);
    acc[0]+=sl*w0.x; acc[1]+=sl*w0.y; acc[2]+=sl*w0.z; acc[3]+=sl*w0.w;
    acc[4]+=sl*w1.x; acc[5]+=sl*w1.y; acc[6]+=sl*w1.z; acc[7]+=sl*w1.w;
  }
#pragma unroll
  for (int e=0;e<8;e++) acc[e] = waveSum(acc[e]);
  if (lane==0){
#pragma unroll
    for (int e=0;e<8;e++)
      fiin[(size_t)b*512 + e*64 + k] = fmaxf(acc[e] + bp[k*8+e], 0.f);
  }
}

// ---- FI linear (+relu+residual) then Set linear (+relu) -> vec_store[l][b][:] ----
__global__ __launch_bounds__(256) void k_fi_set(const float* __restrict__ fiin,
    const float* __restrict__ Wf, const float* __restrict__ bfi,
    const float* __restrict__ Ws, const float* __restrict__ bs,
    float* __restrict__ vecst_l){
  int b = blockIdx.x; int tid = threadIdx.x;
  __shared__ float row[512];
  __shared__ float res[512];
  reinterpret_cast<float2*>(row)[tid] = reinterpret_cast<const float2*>(fiin + (size_t)b*512)[tid];
  __syncthreads();
  float a0=0.f, a1=0.f;
#pragma unroll 4
  for (int d=0; d<512; ++d){
    float rv = row[d];
    float2 w = *reinterpret_cast<const float2*>(Wf + (size_t)d*512 + tid*2);
    a0 += rv * w.x;
    a1 += rv * w.y;
  }
  {
    float2 ub = *reinterpret_cast<const float2*>(bfi + tid*2);
    res[tid*2]   = fmaxf(a0 + ub.x, 0.f) + row[tid*2];
    res[tid*2+1] = fmaxf(a1 + ub.y, 0.f) + row[tid*2+1];
  }
  __syncthreads();
  if (tid < 64){
    float c0=0.f, c1=0.f;
#pragma unroll 4
    for (int d=0; d<512; ++d){
      float rv = res[d];
      float2 w = *reinterpret_cast<const float2*>(Ws + (size_t)d*128 + tid*2);
      c0 += rv*w.x; c1 += rv*w.y;
    }
    float2 ub = *reinterpret_cast<const float2*>(bs + tid*2);
    vecst_l[(size_t)b*128 + tid*2]   = fmaxf(c0 + ub.x, 0.f);
    vecst_l[(size_t)b*128 + tid*2+1] = fmaxf(c1 + ub.y, 0.f);
  }
}

// ---- sum_att, att_dis output, t_emb in-place update with LN ----
__global__ __launch_bounds__(256) void k_update(float* __restrict__ temb, const float* __restrict__ att,
    const float* __restrict__ wp1, const float* __restrict__ bp1,
    const float* __restrict__ gn, const float* __restrict__ ben,
    float* __restrict__ attdis, int layer){
  int bl = blockIdx.x;            // 0..B*L-1
  int tid = threadIdx.x;
  __shared__ float sred[9];
  int wave = tid>>6, lane = tid&63;
  if (tid < 64){
    float a = att[(size_t)bl*64 + tid];
    float t = waveSum(a);
    if (tid==0){
      sred[8] = t;
      int b = bl >> 10, lseq = bl & 1023;
      attdis[(size_t)(layer*B_ + b)*L_ + lseq] = t;
    }
  }
  __syncthreads();
  float sa = sred[8];
  int d0 = tid*2;
  float2 e = *reinterpret_cast<const float2*>(&temb[(size_t)bl*512 + d0]);
  float2 uw  = *reinterpret_cast<const float2*>(wp1 + d0);
  float2 ubp = *reinterpret_cast<const float2*>(bp1 + d0);
  float v0 = e.x * (sa*uw.x + ubp.x + 1.0f);
  float v1 = e.y * (sa*uw.y + ubp.y + 1.0f);
  float s1 = v0+v1, s2 = v0*v0+v1*v1;
  float w1 = waveSum(s1), w2 = waveSum(s2);
  if (lane==0){ sred[wave]=w1; sred[4+wave]=w2; }
  __syncthreads();
  s1 = sred[0]+sred[1]+sred[2]+sred[3];
  s2 = sred[4]+sred[5]+sred[6]+sred[7];
  float m = s1*(1.f/512.f);
  float var = s2*(1.f/512.f) - m*m;
  float rstd = rsqrtf(var+1e-5f);
  float2 ug  = *reinterpret_cast<const float2*>(gn + d0);
  float2 ube = *reinterpret_cast<const float2*>(ben + d0);
  float2 o;
  o.x = (v0-m)*rstd*ug.x + ube.x;
  o.y = (v1-m)*rstd*ug.y + ube.y;
  *reinterpret_cast<float2*>(&temb[(size_t)bl*512 + d0]) = o;
}

// ---- final attention rate ----
__global__ __launch_bounds__(64) void k_aat_rate(const float* __restrict__ temb,
    const float* __restrict__ w_aat, const float* __restrict__ b_aat, float* __restrict__ ratef){
  int bl = blockIdx.x; int lane = threadIdx.x;
  const float* rp = temb + (size_t)bl*512 + lane*8;
  float4 e0 = *reinterpret_cast<const float4*>(rp);
  float4 e1 = *reinterpret_cast<const float4*>(rp+4);
  const float* wp = w_aat + lane*8;
  float4 w0 = *reinterpret_cast<const float4*>(wp);
  float4 w1 = *reinterpret_cast<const float4*>(wp+4);
  float s = e0.x*w0.x+e0.y*w0.y+e0.z*w0.z+e0.w*w0.w
          + e1.x*w1.x+e1.y*w1.y+e1.z*w1.z+e1.w*w1.w;
  s = waveSum(s);
  if (lane==0) ratef[bl] = fmaxf(s + b_aat[0], 0.f);
}

// ---- softmax over contiguous L per b ----
__global__ __launch_bounds__(256) void k_softmax_seq(float* __restrict__ ratef){
  int b = blockIdx.x; int tid = threadIdx.x;
  float* base = ratef + (size_t)b*1024;
  float4 v = reinterpret_cast<float4*>(base)[tid];
  float mx = fmaxf(fmaxf(v.x,v.y),fmaxf(v.z,v.w));
  __shared__ float red[8];
  int wave=tid>>6, lane=tid&63;
  float wm = waveMax(mx);
  if(lane==0) red[wave]=wm;
  __syncthreads();
  mx = fmaxf(fmaxf(red[0],red[1]),fmaxf(red[2],red[3]));
  v.x=__expf(v.x-mx); v.y=__expf(v.y-mx); v.z=__expf(v.z-mx); v.w=__expf(v.w-mx);
  float s = v.x+v.y+v.z+v.w;
  float wsum = waveSum(s);
  if(lane==0) red[4+wave]=wsum;
  __syncthreads();
  s = red[4]+red[5]+red[6]+red[7];
  float inv = 1.f/s;
  v.x*=inv;v.y*=inv;v.z*=inv;v.w*=inv;
  reinterpret_cast<float4*>(base)[tid] = v;
}

// ---- final pool + LN ----
__global__ __launch_bounds__(256) void k_pool(const float* __restrict__ temb, const float* __restrict__ attf,
   const float* __restrict__ g_aat, const float* __restrict__ be_aat, float* __restrict__ spool){
  int b = blockIdx.x; int tid = threadIdx.x;
  __shared__ float sA[1024];
  reinterpret_cast<float4*>(sA)[tid] = reinterpret_cast<const float4*>(attf + (size_t)b*1024)[tid];
  __syncthreads();
  int d0 = tid*2;
  float a0=0.f,a1=0.f;
  for (int l=0;l<1024;++l){
    float2 e = *reinterpret_cast<const float2*>(&temb[((size_t)(b*1024+l))*512 + d0]);
    float av = sA[l];
    a0 += e.x*av; a1 += e.y*av;
  }
  a0 *= 0.03125f; a1 *= 0.03125f;
  __shared__ float red[8];
  int wave=tid>>6,lane=tid&63;
  float s1 = a0+a1, s2 = a0*a0+a1*a1;
  float w1=waveSum(s1), w2=waveSum(s2);
  if(lane==0){red[wave]=w1; red[4+wave]=w2;}
  __syncthreads();
  s1=red[0]+red[1]+red[2]+red[3];
  s2=red[4]+red[5]+red[6]+red[7];
  float m=s1*(1.f/512.f), var=s2*(1.f/512.f)-m*m, rstd=rsqrtf(var+1e-5f);
  float2 ug=*reinterpret_cast<const float2*>(g_aat+d0);
  float2 ub=*reinterpret_cast<const float2*>(be_aat+d0);
  spool[(size_t)b*512+d0]   = (a0-m)*rstd*ug.x+ub.x;
  spool[(size_t)b*512+d0+1] = (a1-m)*rstd*ug.y+ub.y;
}

// ---- final head: P = sigmoid(cat(spool, ott) @ Wh + bh) ----
__global__ __launch_bounds__(256) void k_final(const float* __restrict__ spool, const float* __restrict__ vecst,
    const float* __restrict__ Wh, const float* __restrict__ bh, float* __restrict__ Pout){
  int b = blockIdx.x; int tid = threadIdx.x;
  float part = 0.f;
  for (int i = tid; i < 2560; i += 256){
    float v;
    if (i < 512) v = spool[(size_t)b*512 + i];
    else {
      int j = i - 512;
      v = vecst[(size_t)(j>>7)*(B_*SET_) + b*SET_ + (j&127)];
    }
    part += v * Wh[i];
  }
  __shared__ float red[4];
  int wave=tid>>6,lane=tid&63;
  float w = waveSum(part);
  if(lane==0) red[wave]=w;
  __syncthreads();
  if (tid==0){
    float x = red[0]+red[1]+red[2]+red[3] + bh[0];
    Pout[b] = 1.0f/(1.0f+expf(-x));
  }
}

extern "C" void kernel_launch(void* const* d_in, const int* in_sizes, int n_in,
                              void* d_out, int out_size, void* d_ws, size_t ws_size,
                              hipStream_t stream){
  const float* emb   = (const float*)d_in[0];
  const float* W_att = (const float*)d_in[1];
  const float* b_att = (const float*)d_in[2];
  const float* g_att = (const float*)d_in[3];
  const float* be_att= (const float*)d_in[4];
  const float* W_pro = (const float*)d_in[5];
  const float* b_pro = (const float*)d_in[6];
  const float* w_p1  = (const float*)d_in[7];
  const float* b_p1  = (const float*)d_in[8];
  const float* W_FI  = (const float*)d_in[9];
  const float* b_FI  = (const float*)d_in[10];
  const float* W_Set = (const float*)d_in[11];
  const float* b_Set = (const float*)d_in[12];
  const float* g_n   = (const float*)d_in[13];
  const float* be_n  = (const float*)d_in[14];
  const float* w_aat = (const float*)d_in[15];
  const float* b_aat = (const float*)d_in[16];
  const float* g_aat = (const float*)d_in[17];
  const float* be_aat= (const float*)d_in[18];
  const float* W_h2p = (const float*)d_in[19];
  const float* b_h2p = (const float*)d_in[20];
  float* out = (float*)d_out;

  float* ws = (float*)d_ws;
  float* temb  = ws;                      // 8,388,608
  float* att   = temb + 8388608;          // 1,048,576
  float* spart = att + 1048576;           // 2,097,152
  float* fiin  = spart + 2097152;         // 8,192
  float* vecst = fiin + 8192;             // 131,072
  float* ratef = vecst + 131072;          // 16,384
  float* spool = ratef + 16384;           // 8,192

  hipMemcpyAsync(temb, emb, (size_t)8388608*4, hipMemcpyDeviceToDevice, stream);
  for (int l=0; l<16; ++l){
    k_rate<<<2048,256,0,stream>>>(temb, W_att + (size_t)l*32768, b_att + l*64, att);
    k_softmax<<<1024,256,0,stream>>>(att);
    k_spart<<<dim3(16,4,4),256,0,stream>>>(temb, att, spart);
    k_sln_vec<<<1024,64,0,stream>>>(spart, g_att + (size_t)l*32768, be_att + (size_t)l*32768,
                                    W_pro + (size_t)l*262144, b_pro + l*512, fiin);
    k_fi_set<<<16,256,0,stream>>>(fiin, W_FI + (size_t)l*262144, b_FI + l*512,
                                  W_Set + (size_t)l*65536, b_Set + l*128, vecst + (size_t)l*2048);
    k_update<<<16384,256,0,stream>>>(temb, att, w_p1 + l*512, b_p1 + l*512,
                                     g_n + l*512, be_n + l*512, out + 16, l);
  }
  k_aat_rate<<<16384,64,0,stream>>>(temb, w_aat, b_aat, ratef);
  k_softmax_seq<<<16,256,0,stream>>>(ratef);
  k_pool<<<16,256,0,stream>>>(temb, ratef, g_aat, be_aat, spool);
  k_final<<<16,256,0,stream>>>(spool, vecst, W_h2p, b_h2p, out);
}

// Round 3
// 2905.175 us; speedup vs baseline: 1.2957x; 1.2957x over previous
//
#include <hip/hip_runtime.h>
#include <hip/hip_bf16.h>

#define B_ 16
#define L_ 1024
#define D_ 512
#define K_ 64
#define NL_ 16
#define SMALL_ 8
#define SET_ 128

__device__ inline float waveSum(float v){
#pragma unroll
  for (int o=32;o>0;o>>=1) v += __shfl_down(v,o);
  return v;
}
__device__ inline float waveMax(float v){
#pragma unroll
  for (int o=32;o>0;o>>=1) v = fmaxf(v,__shfl_down(v,o));
  return v;
}

// ---- rate = relu(t_emb @ Wa^T + ba), 8 rows per block ----
__global__ __launch_bounds__(256) void k_rate(const float* __restrict__ temb, const float* __restrict__ Wa,
                                              const float* __restrict__ ba, float* __restrict__ att){
  int row0 = blockIdx.x*8;                 // global row in [0, B*L)
  __shared__ float rows[8][512];
  int tid = threadIdx.x;
  {
    const float4* src = reinterpret_cast<const float4*>(temb + (size_t)row0*512);
    float4* dst = reinterpret_cast<float4*>(&rows[0][0]);
#pragma unroll
    for (int i=0;i<4;i++) dst[tid + i*256] = src[tid + i*256];
  }
  __syncthreads();
  int wave = tid>>6, lane = tid&63;
  for (int h=0; h<16; ++h){
    int k = wave*16 + h;
    const float* wp = Wa + (size_t)k*512 + lane*8;
    float4 w0 = *reinterpret_cast<const float4*>(wp);
    float4 w1 = *reinterpret_cast<const float4*>(wp+4);
    float bav = ba[k];
#pragma unroll
    for (int r=0;r<8;++r){
      const float* rp = &rows[r][lane*8];
      float4 e0 = *reinterpret_cast<const float4*>(rp);
      float4 e1 = *reinterpret_cast<const float4*>(rp+4);
      float s = e0.x*w0.x + e0.y*w0.y + e0.z*w0.z + e0.w*w0.w
              + e1.x*w1.x + e1.y*w1.y + e1.z*w1.z + e1.w*w1.w;
      s = waveSum(s);
      if (lane==0) att[(size_t)(row0 + r)*64 + k] = fmaxf(s + bav, 0.0f);
    }
  }
}

// ---- softmax over sequence dim (axis L) per (b,k), in place on att[B,L,K] ----
__global__ __launch_bounds__(256) void k_softmax(float* __restrict__ att){
  int b = blockIdx.x >> 6, k = blockIdx.x & 63;
  float* base = att + (size_t)b*L_*K_ + k;
  int tid = threadIdx.x;
  float v[4];
  float mx = -1e30f;
#pragma unroll
  for (int i=0;i<4;i++){ v[i] = base[(size_t)(tid + i*256)*64]; mx = fmaxf(mx, v[i]); }
  __shared__ float red[8];
  int wave = tid>>6, lane = tid&63;
  float wm = waveMax(mx);
  if (lane==0) red[wave] = wm;
  __syncthreads();
  mx = fmaxf(fmaxf(red[0],red[1]),fmaxf(red[2],red[3]));
  float sum = 0.f;
#pragma unroll
  for (int i=0;i<4;i++){ v[i] = __expf(v[i]-mx); sum += v[i]; }
  float ws = waveSum(sum);
  if (lane==0) red[4+wave] = ws;
  __syncthreads();
  sum = red[4]+red[5]+red[6]+red[7];
  float inv = 1.0f/sum;
#pragma unroll
  for (int i=0;i<4;i++) base[(size_t)(tid + i*256)*64] = v[i]*inv;
}

// ---- s partials: spart[b][lc][k][d] = sum_{l in chunk} att[b,l,k]*temb[b,l,d] ----
__global__ __launch_bounds__(256) void k_spart(const float* __restrict__ temb, const float* __restrict__ att,
                                               float* __restrict__ spart){
  int b = blockIdx.x, dt = blockIdx.y, lc = blockIdx.z;
  __shared__ float se[8][128];
  __shared__ float sa[8][64];
  int tid = threadIdx.x;
  int r8 = tid>>5;            // 0..7
  int c32 = tid&31;           // 0..31
  float acc[8][4];
#pragma unroll
  for (int i=0;i<8;i++){
#pragma unroll
    for(int j=0;j<4;j++) acc[i][j]=0.f;
  }
  int kg = r8*8;
  int dg = c32*4;
  int lbase = lc*256;
  for (int l0=0; l0<256; l0+=8){
    int l = lbase + l0 + r8;
    *reinterpret_cast<float4*>(&se[r8][c32*4]) =
      *reinterpret_cast<const float4*>(&temb[((size_t)(b*L_ + l))*512 + dt*128 + c32*4]);
    *reinterpret_cast<float2*>(&sa[r8][c32*2]) =
      *reinterpret_cast<const float2*>(&att[((size_t)(b*L_ + l))*64 + c32*2]);
    __syncthreads();
#pragma unroll 1
    for (int i=0;i<8;i++){
      float4 e = *reinterpret_cast<const float4*>(&se[i][dg]);
      float4 A0 = *reinterpret_cast<const float4*>(&sa[i][kg]);
      float4 A1 = *reinterpret_cast<const float4*>(&sa[i][kg+4]);
      float a[8];
      a[0]=A0.x;a[1]=A0.y;a[2]=A0.z;a[3]=A0.w;a[4]=A1.x;a[5]=A1.y;a[6]=A1.z;a[7]=A1.w;
#pragma unroll
      for (int kk=0;kk<8;kk++){
        acc[kk][0] += a[kk]*e.x;
        acc[kk][1] += a[kk]*e.y;
        acc[kk][2] += a[kk]*e.z;
        acc[kk][3] += a[kk]*e.w;
      }
    }
    __syncthreads();
  }
#pragma unroll
  for (int kk=0;kk<8;kk++){
    float4 o; o.x=acc[kk][0];o.y=acc[kk][1];o.z=acc[kk][2];o.w=acc[kk][3];
    *reinterpret_cast<float4*>(&spart[((size_t)((b*4+lc)*64 + kg+kk))*512 + dt*128 + dg]) = o;
  }
}

// ---- reduce partials, scale, LN(ga,bea), vec = relu(s@Wp+bp) -> fiin[b][e*64+k] ----
__global__ __launch_bounds__(64) void k_sln_vec(const float* __restrict__ spart,
     const float* __restrict__ ga, const float* __restrict__ bea,
     const float* __restrict__ Wp, const float* __restrict__ bp,
     float* __restrict__ fiin){
  int bk = blockIdx.x; int b = bk>>6, k = bk&63;
  int lane = threadIdx.x;
  int d0 = lane*8;
  float sv[8];
#pragma unroll
  for (int j=0;j<8;j++) sv[j]=0.f;
#pragma unroll
  for (int lc=0;lc<4;lc++){
    const float* p = spart + ((size_t)((b*4+lc)*64 + k))*512 + d0;
    float4 x0 = *reinterpret_cast<const float4*>(p);
    float4 x1 = *reinterpret_cast<const float4*>(p+4);
    sv[0]+=x0.x; sv[1]+=x0.y; sv[2]+=x0.z; sv[3]+=x0.w;
    sv[4]+=x1.x; sv[5]+=x1.y; sv[6]+=x1.z; sv[7]+=x1.w;
  }
  const float inv_sqrt_L = 0.03125f;
  float s1=0.f, s2=0.f;
#pragma unroll
  for (int j=0;j<8;j++){ sv[j]*=inv_sqrt_L; s1+=sv[j]; s2+=sv[j]*sv[j]; }
#pragma unroll
  for (int o=32;o>0;o>>=1){ s1 += __shfl_xor(s1,o); s2 += __shfl_xor(s2,o); }
  float m = s1*(1.0f/512.0f);
  float var = s2*(1.0f/512.0f) - m*m;
  float rstd = rsqrtf(var + 1e-5f);
  const float* gap = ga + (size_t)k*512 + d0;
  const float* bep = bea + (size_t)k*512 + d0;
  float4 g0 = *reinterpret_cast<const float4*>(gap);
  float4 g1 = *reinterpret_cast<const float4*>(gap+4);
  float4 e0 = *reinterpret_cast<const float4*>(bep);
  float4 e1 = *reinterpret_cast<const float4*>(bep+4);
  float gav[8] = {g0.x,g0.y,g0.z,g0.w,g1.x,g1.y,g1.z,g1.w};
  float bev[8] = {e0.x,e0.y,e0.z,e0.w,e1.x,e1.y,e1.z,e1.w};
  float acc[8];
#pragma unroll
  for (int e=0;e<8;e++) acc[e]=0.f;
#pragma unroll
  for (int j=0;j<8;j++){
    float sl = (sv[j]-m)*rstd*gav[j] + bev[j];
    const float* wp = Wp + ((size_t)k*512 + d0 + j)*8;
    float4 w0 = *reinterpret_cast<const float4*>(wp);
    float4 w1 = *reinterpret_cast<const float4*>(wp+4);
    acc[0]+=sl*w0.x; acc[1]+=sl*w0.y; acc[2]+=sl*w0.z; acc[3]+=sl*w0.w;
    acc[4]+=sl*w1.x; acc[5]+=sl*w1.y; acc[6]+=sl*w1.z; acc[7]+=sl*w1.w;
  }
#pragma unroll
  for (int e=0;e<8;e++) acc[e] = waveSum(acc[e]);
  if (lane==0){
#pragma unroll
    for (int e=0;e<8;e++)
      fiin[(size_t)b*512 + e*64 + k] = fmaxf(acc[e] + bp[k*8+e], 0.f);
  }
}

// ---- FI linear (+relu+residual): res[b][o] over grid (oc=8, b=16) ----
__global__ __launch_bounds__(256) void k_fi(const float* __restrict__ fiin,
    const float* __restrict__ Wf, const float* __restrict__ bfi, float* __restrict__ res){
  int oc = blockIdx.x, b = blockIdx.y;
  int tid = threadIdx.x;
  int og = tid & 63, q = tid >> 6;
  int o = oc*64 + og;
  __shared__ float row[512];
  __shared__ float part[4][64];
  reinterpret_cast<float2*>(row)[tid] = reinterpret_cast<const float2*>(fiin + (size_t)b*512)[tid];
  __syncthreads();
  float acc = 0.f;
  const float* wp = Wf + (size_t)(q*128)*512 + o;
  const float* rp = &row[q*128];
#pragma unroll 4
  for (int d=0; d<128; ++d) acc += rp[d] * wp[(size_t)d*512];
  part[q][og] = acc;
  __syncthreads();
  if (q==0){
    float s = part[0][og]+part[1][og]+part[2][og]+part[3][og];
    res[(size_t)b*512 + o] = fmaxf(s + bfi[o], 0.f) + row[o];
  }
}

// ---- Set linear (+relu): vec[b][o2] over grid (oc=2, b=16) ----
__global__ __launch_bounds__(256) void k_set(const float* __restrict__ res,
    const float* __restrict__ Ws, const float* __restrict__ bs, float* __restrict__ vecst_l){
  int oc = blockIdx.x, b = blockIdx.y;
  int tid = threadIdx.x;
  int og = tid & 63, q = tid >> 6;
  int o = oc*64 + og;
  __shared__ float row[512];
  __shared__ float part[4][64];
  reinterpret_cast<float2*>(row)[tid] = reinterpret_cast<const float2*>(res + (size_t)b*512)[tid];
  __syncthreads();
  float acc = 0.f;
  const float* wp = Ws + (size_t)(q*128)*128 + o;
  const float* rp = &row[q*128];
#pragma unroll 4
  for (int d=0; d<128; ++d) acc += rp[d] * wp[(size_t)d*128];
  part[q][og] = acc;
  __syncthreads();
  if (q==0){
    vecst_l[(size_t)b*128 + o] = fmaxf(part[0][og]+part[1][og]+part[2][og]+part[3][og] + bs[o], 0.f);
  }
}

// ---- sum_att, att_dis output, t_emb in-place update with LN ----
__global__ __launch_bounds__(256) void k_update(float* __restrict__ temb, const float* __restrict__ att,
    const float* __restrict__ wp1, const float* __restrict__ bp1,
    const float* __restrict__ gn, const float* __restrict__ ben,
    float* __restrict__ attdis, int layer){
  int bl = blockIdx.x;            // 0..B*L-1
  int tid = threadIdx.x;
  __shared__ float sred[9];
  int wave = tid>>6, lane = tid&63;
  if (tid < 64){
    float a = att[(size_t)bl*64 + tid];
    float t = waveSum(a);
    if (tid==0){
      sred[8] = t;
      int b = bl >> 10, lseq = bl & 1023;
      attdis[(size_t)(layer*B_ + b)*L_ + lseq] = t;
    }
  }
  __syncthreads();
  float sa = sred[8];
  int d0 = tid*2;
  float2 e = *reinterpret_cast<const float2*>(&temb[(size_t)bl*512 + d0]);
  float2 uw  = *reinterpret_cast<const float2*>(wp1 + d0);
  float2 ubp = *reinterpret_cast<const float2*>(bp1 + d0);
  float v0 = e.x * (sa*uw.x + ubp.x + 1.0f);
  float v1 = e.y * (sa*uw.y + ubp.y + 1.0f);
  float s1 = v0+v1, s2 = v0*v0+v1*v1;
  float w1 = waveSum(s1), w2 = waveSum(s2);
  if (lane==0){ sred[wave]=w1; sred[4+wave]=w2; }
  __syncthreads();
  s1 = sred[0]+sred[1]+sred[2]+sred[3];
  s2 = sred[4]+sred[5]+sred[6]+sred[7];
  float m = s1*(1.f/512.f);
  float var = s2*(1.f/512.f) - m*m;
  float rstd = rsqrtf(var+1e-5f);
  float2 ug  = *reinterpret_cast<const float2*>(gn + d0);
  float2 ube = *reinterpret_cast<const float2*>(ben + d0);
  float2 o;
  o.x = (v0-m)*rstd*ug.x + ube.x;
  o.y = (v1-m)*rstd*ug.y + ube.y;
  *reinterpret_cast<float2*>(&temb[(size_t)bl*512 + d0]) = o;
}

// ---- final attention rate ----
__global__ __launch_bounds__(64) void k_aat_rate(const float* __restrict__ temb,
    const float* __restrict__ w_aat, const float* __restrict__ b_aat, float* __restrict__ ratef){
  int bl = blockIdx.x; int lane = threadIdx.x;
  const float* rp = temb + (size_t)bl*512 + lane*8;
  float4 e0 = *reinterpret_cast<const float4*>(rp);
  float4 e1 = *reinterpret_cast<const float4*>(rp+4);
  const float* wp = w_aat + lane*8;
  float4 w0 = *reinterpret_cast<const float4*>(wp);
  float4 w1 = *reinterpret_cast<const float4*>(wp+4);
  float s = e0.x*w0.x+e0.y*w0.y+e0.z*w0.z+e0.w*w0.w
          + e1.x*w1.x+e1.y*w1.y+e1.z*w1.z+e1.w*w1.w;
  s = waveSum(s);
  if (lane==0) ratef[bl] = fmaxf(s + b_aat[0], 0.f);
}

// ---- softmax over contiguous L per b ----
__global__ __launch_bounds__(256) void k_softmax_seq(float* __restrict__ ratef){
  int b = blockIdx.x; int tid = threadIdx.x;
  float* base = ratef + (size_t)b*1024;
  float4 v = reinterpret_cast<float4*>(base)[tid];
  float mx = fmaxf(fmaxf(v.x,v.y),fmaxf(v.z,v.w));
  __shared__ float red[8];
  int wave=tid>>6, lane=tid&63;
  float wm = waveMax(mx);
  if(lane==0) red[wave]=wm;
  __syncthreads();
  mx = fmaxf(fmaxf(red[0],red[1]),fmaxf(red[2],red[3]));
  v.x=__expf(v.x-mx); v.y=__expf(v.y-mx); v.z=__expf(v.z-mx); v.w=__expf(v.w-mx);
  float s = v.x+v.y+v.z+v.w;
  float wsum = waveSum(s);
  if(lane==0) red[4+wave]=wsum;
  __syncthreads();
  s = red[4]+red[5]+red[6]+red[7];
  float inv = 1.f/s;
  v.x*=inv;v.y*=inv;v.z*=inv;v.w*=inv;
  reinterpret_cast<float4*>(base)[tid] = v;
}

// ---- final pool partials: sraw[b][d] = (1/32) * sum_l temb[b][l][d]*attf[b][l] ----
__global__ __launch_bounds__(256) void k_poolA(const float* __restrict__ temb, const float* __restrict__ attf,
                                               float* __restrict__ sraw){
  int dc = blockIdx.x, b = blockIdx.y;
  int tid = threadIdx.x;
  int dl = tid & 63, q = tid >> 6;
  int d = dc*64 + dl;
  __shared__ float sA[1024];
  __shared__ float part[4][64];
  reinterpret_cast<float4*>(sA)[tid] = reinterpret_cast<const float4*>(attf + (size_t)b*1024)[tid];
  __syncthreads();
  float acc = 0.f;
  const float* tp = temb + ((size_t)b*1024 + q*256)*512 + d;
  const float* ap = &sA[q*256];
#pragma unroll 4
  for (int l=0;l<256;++l) acc += tp[(size_t)l*512]*ap[l];
  part[q][dl] = acc;
  __syncthreads();
  if (q==0) sraw[(size_t)b*512 + d] = (part[0][dl]+part[1][dl]+part[2][dl]+part[3][dl])*0.03125f;
}

// ---- final pool LN ----
__global__ __launch_bounds__(256) void k_poolB(const float* __restrict__ sraw,
   const float* __restrict__ g_aat, const float* __restrict__ be_aat, float* __restrict__ spool){
  int b = blockIdx.x; int tid = threadIdx.x;
  int d0 = tid*2;
  float2 a = *reinterpret_cast<const float2*>(&sraw[(size_t)b*512 + d0]);
  __shared__ float red[8];
  int wave=tid>>6,lane=tid&63;
  float s1 = a.x+a.y, s2 = a.x*a.x+a.y*a.y;
  float w1=waveSum(s1), w2=waveSum(s2);
  if(lane==0){red[wave]=w1; red[4+wave]=w2;}
  __syncthreads();
  s1=red[0]+red[1]+red[2]+red[3];
  s2=red[4]+red[5]+red[6]+red[7];
  float m=s1*(1.f/512.f), var=s2*(1.f/512.f)-m*m, rstd=rsqrtf(var+1e-5f);
  float2 ug=*reinterpret_cast<const float2*>(g_aat+d0);
  float2 ub=*reinterpret_cast<const float2*>(be_aat+d0);
  spool[(size_t)b*512+d0]   = (a.x-m)*rstd*ug.x+ub.x;
  spool[(size_t)b*512+d0+1] = (a.y-m)*rstd*ug.y+ub.y;
}

// ---- final head: P = sigmoid(cat(spool, ott) @ Wh + bh) ----
__global__ __launch_bounds__(256) void k_final(const float* __restrict__ spool, const float* __restrict__ vecst,
    const float* __restrict__ Wh, const float* __restrict__ bh, float* __restrict__ Pout){
  int b = blockIdx.x; int tid = threadIdx.x;
  float part = 0.f;
  for (int i = tid; i < 2560; i += 256){
    float v;
    if (i < 512) v = spool[(size_t)b*512 + i];
    else {
      int j = i - 512;
      v = vecst[(size_t)(j>>7)*(B_*SET_) + b*SET_ + (j&127)];
    }
    part += v * Wh[i];
  }
  __shared__ float red[4];
  int wave=tid>>6,lane=tid&63;
  float w = waveSum(part);
  if(lane==0) red[wave]=w;
  __syncthreads();
  if (tid==0){
    float x = red[0]+red[1]+red[2]+red[3] + bh[0];
    Pout[b] = 1.0f/(1.0f+expf(-x));
  }
}

extern "C" void kernel_launch(void* const* d_in, const int* in_sizes, int n_in,
                              void* d_out, int out_size, void* d_ws, size_t ws_size,
                              hipStream_t stream){
  const float* emb   = (const float*)d_in[0];
  const float* W_att = (const float*)d_in[1];
  const float* b_att = (const float*)d_in[2];
  const float* g_att = (const float*)d_in[3];
  const float* be_att= (const float*)d_in[4];
  const float* W_pro = (const float*)d_in[5];
  const float* b_pro = (const float*)d_in[6];
  const float* w_p1  = (const float*)d_in[7];
  const float* b_p1  = (const float*)d_in[8];
  const float* W_FI  = (const float*)d_in[9];
  const float* b_FI  = (const float*)d_in[10];
  const float* W_Set = (const float*)d_in[11];
  const float* b_Set = (const float*)d_in[12];
  const float* g_n   = (const float*)d_in[13];
  const float* be_n  = (const float*)d_in[14];
  const float* w_aat = (const float*)d_in[15];
  const float* b_aat = (const float*)d_in[16];
  const float* g_aat = (const float*)d_in[17];
  const float* be_aat= (const float*)d_in[18];
  const float* W_h2p = (const float*)d_in[19];
  const float* b_h2p = (const float*)d_in[20];
  float* out = (float*)d_out;

  float* ws = (float*)d_ws;
  float* temb  = ws;                      // 8,388,608
  float* att   = temb + 8388608;          // 1,048,576
  float* spart = att + 1048576;           // 2,097,152
  float* fiin  = spart + 2097152;         // 8,192
  float* vecst = fiin + 8192;             // 131,072
  float* ratef = vecst + 131072;          // 16,384
  float* spool = ratef + 16384;           // 8,192
  float* res   = spool + 8192;            // 8,192
  float* sraw  = res + 8192;              // 8,192

  hipMemcpyAsync(temb, emb, (size_t)8388608*4, hipMemcpyDeviceToDevice, stream);
  for (int l=0; l<16; ++l){
    k_rate<<<2048,256,0,stream>>>(temb, W_att + (size_t)l*32768, b_att + l*64, att);
    k_softmax<<<1024,256,0,stream>>>(att);
    k_spart<<<dim3(16,4,4),256,0,stream>>>(temb, att, spart);
    k_sln_vec<<<1024,64,0,stream>>>(spart, g_att + (size_t)l*32768, be_att + (size_t)l*32768,
                                    W_pro + (size_t)l*262144, b_pro + l*512, fiin);
    k_fi<<<dim3(8,16),256,0,stream>>>(fiin, W_FI + (size_t)l*262144, b_FI + l*512, res);
    k_set<<<dim3(2,16),256,0,stream>>>(res, W_Set + (size_t)l*65536, b_Set + l*128,
                                       vecst + (size_t)l*2048);
    k_update<<<16384,256,0,stream>>>(temb, att, w_p1 + l*512, b_p1 + l*512,
                                     g_n + l*512, be_n + l*512, out + 16, l);
  }
  k_aat_rate<<<16384,64,0,stream>>>(temb, w_aat, b_aat, ratef);
  k_softmax_seq<<<16,256,0,stream>>>(ratef);
  k_poolA<<<dim3(8,16),256,0,stream>>>(temb, ratef, sraw);
  k_poolB<<<16,256,0,stream>>>(sraw, g_aat, be_aat, spool);
  k_final<<<16,256,0,stream>>>(spool, vecst, W_h2p, b_h2p, out);
}

// Round 4
// 1850.222 us; speedup vs baseline: 2.0345x; 1.5702x over previous
//
#include <hip/hip_runtime.h>
#include <hip/hip_bf16.h>

#define B_ 16
#define L_ 1024
#define D_ 512
#define K_ 64
#define NL_ 16
#define SMALL_ 8
#define SET_ 128

__device__ inline float waveSum(float v){
#pragma unroll
  for (int o=32;o>0;o>>=1) v += __shfl_down(v,o);
  return v;
}
__device__ inline float waveMax(float v){
#pragma unroll
  for (int o=32;o>0;o>>=1) v = fmaxf(v,__shfl_down(v,o));
  return v;
}

// ---- rate GEMM: att_t[b][h][l] = relu( temb[b,l,:] . Wa[h,:] + ba[h] )
// C[16384 rows x 64 heads]; block = 32 rows x 64 heads; thread = 2x4.
__global__ __launch_bounds__(256) void k_rate_gemm(const float* __restrict__ temb,
    const float* __restrict__ Wa, const float* __restrict__ ba, float* __restrict__ att_t){
  int r0 = blockIdx.x*32;            // global row (b*1024 + l), tile within one b
  __shared__ float At[64][36];       // [k][row]
  __shared__ float Bt[64][68];       // [k][h]
  int t = threadIdx.x;
  int tc = t & 15, tr = t >> 4;      // tc -> 4 heads, tr -> 2 rows
  float acc[2][4] = {{0.f,0.f,0.f,0.f},{0.f,0.f,0.f,0.f}};
  for (int kc=0; kc<512; kc+=64){
#pragma unroll
    for (int i=0;i<2;i++){           // stage A: 32 rows x 64 k
      int idx = i*256 + t;
      int row = idx>>4, kq = idx&15;
      float4 v = *reinterpret_cast<const float4*>(temb + (size_t)(r0+row)*512 + kc + kq*4);
      At[kq*4+0][row]=v.x; At[kq*4+1][row]=v.y; At[kq*4+2][row]=v.z; At[kq*4+3][row]=v.w;
    }
#pragma unroll
    for (int i=0;i<4;i++){           // stage B with transpose: Wa[h][k] -> Bt[k][h]
      int idx = i*256 + t;
      int h = idx>>4, kq = idx&15;
      float4 v = *reinterpret_cast<const float4*>(Wa + (size_t)h*512 + kc + kq*4);
      Bt[kq*4+0][h]=v.x; Bt[kq*4+1][h]=v.y; Bt[kq*4+2][h]=v.z; Bt[kq*4+3][h]=v.w;
    }
    __syncthreads();
#pragma unroll 8
    for (int k=0;k<64;++k){
      float2 a = *reinterpret_cast<const float2*>(&At[k][tr*2]);
      float4 b = *reinterpret_cast<const float4*>(&Bt[k][tc*4]);
      acc[0][0]+=a.x*b.x; acc[0][1]+=a.x*b.y; acc[0][2]+=a.x*b.z; acc[0][3]+=a.x*b.w;
      acc[1][0]+=a.y*b.x; acc[1][1]+=a.y*b.y; acc[1][2]+=a.y*b.z; acc[1][3]+=a.y*b.w;
    }
    __syncthreads();
  }
  int bb = r0 >> 10;
  int l0 = r0 & 1023;
#pragma unroll
  for (int i=0;i<4;i++){
    int h = tc*4 + i;
    float bav = ba[h];
#pragma unroll
    for (int j=0;j<2;j++){
      int l = l0 + tr*2 + j;
      att_t[((size_t)(bb*64+h))*1024 + l] = fmaxf(acc[j][i] + bav, 0.f);
    }
  }
}

// ---- spart GEMM: spart[b][lc][k][d] = sum_{l in chunk} att_t[b,k,l]*temb[b,l,d]
// per (b,lc): C[64 k x 64 d window]; thread = 4x4.
__global__ __launch_bounds__(256) void k_spart_gemm(const float* __restrict__ temb,
    const float* __restrict__ att_t, float* __restrict__ spart){
  int dt = blockIdx.x;   // 0..7
  int lc = blockIdx.y;   // 0..3
  int b  = blockIdx.z;
  __shared__ float At[32][68];   // [l][k]
  __shared__ float Bt[32][68];   // [l][d]
  int t = threadIdx.x;
  int tc = t & 15, tr = t >> 4;  // tc -> 4 d, tr -> 4 k
  float acc[4][4] = {{0,0,0,0},{0,0,0,0},{0,0,0,0},{0,0,0,0}};
  int lbase = lc*256;
  for (int ls=0; ls<256; ls+=32){
#pragma unroll
    for (int i=0;i<2;i++){         // stage A with transpose: att_t[k][l] -> At[l][k]
      int idx = i*256 + t;
      int k = idx>>3, lq = idx&7;
      float4 v = *reinterpret_cast<const float4*>(att_t + ((size_t)(b*64+k))*1024 + lbase + ls + lq*4);
      At[lq*4+0][k]=v.x; At[lq*4+1][k]=v.y; At[lq*4+2][k]=v.z; At[lq*4+3][k]=v.w;
    }
#pragma unroll
    for (int i=0;i<2;i++){         // stage B direct: temb rows
      int idx = i*256 + t;
      int l = idx>>4, dq = idx&15;
      *reinterpret_cast<float4*>(&Bt[l][dq*4]) =
        *reinterpret_cast<const float4*>(temb + ((size_t)(b*1024) + lbase + ls + l)*512 + dt*64 + dq*4);
    }
    __syncthreads();
#pragma unroll 8
    for (int l=0;l<32;++l){
      float4 a = *reinterpret_cast<const float4*>(&At[l][tr*4]);
      float4 bb = *reinterpret_cast<const float4*>(&Bt[l][tc*4]);
      acc[0][0]+=a.x*bb.x; acc[0][1]+=a.x*bb.y; acc[0][2]+=a.x*bb.z; acc[0][3]+=a.x*bb.w;
      acc[1][0]+=a.y*bb.x; acc[1][1]+=a.y*bb.y; acc[1][2]+=a.y*bb.z; acc[1][3]+=a.y*bb.w;
      acc[2][0]+=a.z*bb.x; acc[2][1]+=a.z*bb.y; acc[2][2]+=a.z*bb.z; acc[2][3]+=a.z*bb.w;
      acc[3][0]+=a.w*bb.x; acc[3][1]+=a.w*bb.y; acc[3][2]+=a.w*bb.z; acc[3][3]+=a.w*bb.w;
    }
    __syncthreads();
  }
#pragma unroll
  for (int i=0;i<4;i++){
    float4 o; o.x=acc[i][0]; o.y=acc[i][1]; o.z=acc[i][2]; o.w=acc[i][3];
    *reinterpret_cast<float4*>(&spart[((size_t)((b*4+lc)*64 + tr*4+i))*512 + dt*64 + tc*4]) = o;
  }
}

// ---- reduce partials, scale, LN(ga,bea), vec = relu(s@Wp+bp) -> fiin[b][e*64+k] ----
__global__ __launch_bounds__(64) void k_sln_vec(const float* __restrict__ spart,
     const float* __restrict__ ga, const float* __restrict__ bea,
     const float* __restrict__ Wp, const float* __restrict__ bp,
     float* __restrict__ fiin){
  int bk = blockIdx.x; int b = bk>>6, k = bk&63;
  int lane = threadIdx.x;
  int d0 = lane*8;
  float sv[8];
#pragma unroll
  for (int j=0;j<8;j++) sv[j]=0.f;
#pragma unroll
  for (int lc=0;lc<4;lc++){
    const float* p = spart + ((size_t)((b*4+lc)*64 + k))*512 + d0;
    float4 x0 = *reinterpret_cast<const float4*>(p);
    float4 x1 = *reinterpret_cast<const float4*>(p+4);
    sv[0]+=x0.x; sv[1]+=x0.y; sv[2]+=x0.z; sv[3]+=x0.w;
    sv[4]+=x1.x; sv[5]+=x1.y; sv[6]+=x1.z; sv[7]+=x1.w;
  }
  const float inv_sqrt_L = 0.03125f;
  float s1=0.f, s2=0.f;
#pragma unroll
  for (int j=0;j<8;j++){ sv[j]*=inv_sqrt_L; s1+=sv[j]; s2+=sv[j]*sv[j]; }
#pragma unroll
  for (int o=32;o>0;o>>=1){ s1 += __shfl_xor(s1,o); s2 += __shfl_xor(s2,o); }
  float m = s1*(1.0f/512.0f);
  float var = s2*(1.0f/512.0f) - m*m;
  float rstd = rsqrtf(var + 1e-5f);
  const float* gap = ga + (size_t)k*512 + d0;
  const float* bep = bea + (size_t)k*512 + d0;
  float4 g0 = *reinterpret_cast<const float4*>(gap);
  float4 g1 = *reinterpret_cast<const float4*>(gap+4);
  float4 e0 = *reinterpret_cast<const float4*>(bep);
  float4 e1 = *reinterpret_cast<const float4*>(bep+4);
  float gav[8] = {g0.x,g0.y,g0.z,g0.w,g1.x,g1.y,g1.z,g1.w};
  float bev[8] = {e0.x,e0.y,e0.z,e0.w,e1.x,e1.y,e1.z,e1.w};
  float acc[8];
#pragma unroll
  for (int e=0;e<8;e++) acc[e]=0.f;
#pragma unroll
  for (int j=0;j<8;j++){
    float sl = (sv[j]-m)*rstd*gav[j] + bev[j];
    const float* wp = Wp + ((size_t)k*512 + d0 + j)*8;
    float4 w0 = *reinterpret_cast<const float4*>(wp);
    float4 w1 = *reinterpret_cast<const float4*>(wp+4);
    acc[0]+=sl*w0.x; acc[1]+=sl*w0.y; acc[2]+=sl*w0.z; acc[3]+=sl*w0.w;
    acc[4]+=sl*w1.x; acc[5]+=sl*w1.y; acc[6]+=sl*w1.z; acc[7]+=sl*w1.w;
  }
#pragma unroll
  for (int e=0;e<8;e++) acc[e] = waveSum(acc[e]);
  if (lane==0){
#pragma unroll
    for (int e=0;e<8;e++)
      fiin[(size_t)b*512 + e*64 + k] = fmaxf(acc[e] + bp[k*8+e], 0.f);
  }
}

// ---- FI linear (+relu+residual): res[b][o] over grid (oc=8, b=16) ----
__global__ __launch_bounds__(256) void k_fi(const float* __restrict__ fiin,
    const float* __restrict__ Wf, const float* __restrict__ bfi, float* __restrict__ res){
  int oc = blockIdx.x, b = blockIdx.y;
  int tid = threadIdx.x;
  int og = tid & 63, q = tid >> 6;
  int o = oc*64 + og;
  __shared__ float row[512];
  __shared__ float part[4][64];
  reinterpret_cast<float2*>(row)[tid] = reinterpret_cast<const float2*>(fiin + (size_t)b*512)[tid];
  __syncthreads();
  float acc = 0.f;
  const float* wp = Wf + (size_t)(q*128)*512 + o;
  const float* rp = &row[q*128];
#pragma unroll 4
  for (int d=0; d<128; ++d) acc += rp[d] * wp[(size_t)d*512];
  part[q][og] = acc;
  __syncthreads();
  if (q==0){
    float s = part[0][og]+part[1][og]+part[2][og]+part[3][og];
    res[(size_t)b*512 + o] = fmaxf(s + bfi[o], 0.f) + row[o];
  }
}

// ---- Set linear (+relu): vec[b][o2] over grid (oc=2, b=16) ----
__global__ __launch_bounds__(256) void k_set(const float* __restrict__ res,
    const float* __restrict__ Ws, const float* __restrict__ bs, float* __restrict__ vecst_l){
  int oc = blockIdx.x, b = blockIdx.y;
  int tid = threadIdx.x;
  int og = tid & 63, q = tid >> 6;
  int o = oc*64 + og;
  __shared__ float row[512];
  __shared__ float part[4][64];
  reinterpret_cast<float2*>(row)[tid] = reinterpret_cast<const float2*>(res + (size_t)b*512)[tid];
  __syncthreads();
  float acc = 0.f;
  const float* wp = Ws + (size_t)(q*128)*128 + o;
  const float* rp = &row[q*128];
#pragma unroll 4
  for (int d=0; d<128; ++d) acc += rp[d] * wp[(size_t)d*128];
  part[q][og] = acc;
  __syncthreads();
  if (q==0){
    vecst_l[(size_t)b*128 + o] = fmaxf(part[0][og]+part[1][og]+part[2][og]+part[3][og] + bs[o], 0.f);
  }
}

// ---- sum_att (over heads, from att_t), att_dis output, t_emb in-place update with LN ----
__global__ __launch_bounds__(256) void k_update(float* __restrict__ temb, const float* __restrict__ att_t,
    const float* __restrict__ wp1, const float* __restrict__ bp1,
    const float* __restrict__ gn, const float* __restrict__ ben,
    float* __restrict__ attdis, int layer){
  int bl = blockIdx.x;            // 0..B*L-1
  int tid = threadIdx.x;
  __shared__ float sred[9];
  int wave = tid>>6, lane = tid&63;
  if (tid < 64){
    int b = bl >> 10, lseq = bl & 1023;
    float a = att_t[((size_t)(b*64 + tid))*1024 + lseq];
    float t = waveSum(a);
    if (tid==0){
      sred[8] = t;
      attdis[(size_t)(layer*B_ + b)*L_ + lseq] = t;
    }
  }
  __syncthreads();
  float sa = sred[8];
  int d0 = tid*2;
  float2 e = *reinterpret_cast<const float2*>(&temb[(size_t)bl*512 + d0]);
  float2 uw  = *reinterpret_cast<const float2*>(wp1 + d0);
  float2 ubp = *reinterpret_cast<const float2*>(bp1 + d0);
  float v0 = e.x * (sa*uw.x + ubp.x + 1.0f);
  float v1 = e.y * (sa*uw.y + ubp.y + 1.0f);
  float s1 = v0+v1, s2 = v0*v0+v1*v1;
  float w1 = waveSum(s1), w2 = waveSum(s2);
  if (lane==0){ sred[wave]=w1; sred[4+wave]=w2; }
  __syncthreads();
  s1 = sred[0]+sred[1]+sred[2]+sred[3];
  s2 = sred[4]+sred[5]+sred[6]+sred[7];
  float m = s1*(1.f/512.f);
  float var = s2*(1.f/512.f) - m*m;
  float rstd = rsqrtf(var+1e-5f);
  float2 ug  = *reinterpret_cast<const float2*>(gn + d0);
  float2 ube = *reinterpret_cast<const float2*>(ben + d0);
  float2 o;
  o.x = (v0-m)*rstd*ug.x + ube.x;
  o.y = (v1-m)*rstd*ug.y + ube.y;
  *reinterpret_cast<float2*>(&temb[(size_t)bl*512 + d0]) = o;
}

// ---- final attention rate ----
__global__ __launch_bounds__(64) void k_aat_rate(const float* __restrict__ temb,
    const float* __restrict__ w_aat, const float* __restrict__ b_aat, float* __restrict__ ratef){
  int bl = blockIdx.x; int lane = threadIdx.x;
  const float* rp = temb + (size_t)bl*512 + lane*8;
  float4 e0 = *reinterpret_cast<const float4*>(rp);
  float4 e1 = *reinterpret_cast<const float4*>(rp+4);
  const float* wp = w_aat + lane*8;
  float4 w0 = *reinterpret_cast<const float4*>(wp);
  float4 w1 = *reinterpret_cast<const float4*>(wp+4);
  float s = e0.x*w0.x+e0.y*w0.y+e0.z*w0.z+e0.w*w0.w
          + e1.x*w1.x+e1.y*w1.y+e1.z*w1.z+e1.w*w1.w;
  s = waveSum(s);
  if (lane==0) ratef[bl] = fmaxf(s + b_aat[0], 0.f);
}

// ---- softmax over a contiguous 1024-row per block (used for att_t rows and final) ----
__global__ __launch_bounds__(256) void k_softmax_seq(float* __restrict__ ratef){
  int b = blockIdx.x; int tid = threadIdx.x;
  float* base = ratef + (size_t)b*1024;
  float4 v = reinterpret_cast<float4*>(base)[tid];
  float mx = fmaxf(fmaxf(v.x,v.y),fmaxf(v.z,v.w));
  __shared__ float red[8];
  int wave=tid>>6, lane=tid&63;
  float wm = waveMax(mx);
  if(lane==0) red[wave]=wm;
  __syncthreads();
  mx = fmaxf(fmaxf(red[0],red[1]),fmaxf(red[2],red[3]));
  v.x=__expf(v.x-mx); v.y=__expf(v.y-mx); v.z=__expf(v.z-mx); v.w=__expf(v.w-mx);
  float s = v.x+v.y+v.z+v.w;
  float wsum = waveSum(s);
  if(lane==0) red[4+wave]=wsum;
  __syncthreads();
  s = red[4]+red[5]+red[6]+red[7];
  float inv = 1.f/s;
  v.x*=inv;v.y*=inv;v.z*=inv;v.w*=inv;
  reinterpret_cast<float4*>(base)[tid] = v;
}

// ---- final pool partials: sraw[b][d] = (1/32) * sum_l temb[b][l][d]*attf[b][l] ----
__global__ __launch_bounds__(256) void k_poolA(const float* __restrict__ temb, const float* __restrict__ attf,
                                               float* __restrict__ sraw){
  int dc = blockIdx.x, b = blockIdx.y;
  int tid = threadIdx.x;
  int dl = tid & 63, q = tid >> 6;
  int d = dc*64 + dl;
  __shared__ float sA[1024];
  __shared__ float part[4][64];
  reinterpret_cast<float4*>(sA)[tid] = reinterpret_cast<const float4*>(attf + (size_t)b*1024)[tid];
  __syncthreads();
  float acc = 0.f;
  const float* tp = temb + ((size_t)b*1024 + q*256)*512 + d;
  const float* ap = &sA[q*256];
#pragma unroll 4
  for (int l=0;l<256;++l) acc += tp[(size_t)l*512]*ap[l];
  part[q][dl] = acc;
  __syncthreads();
  if (q==0) sraw[(size_t)b*512 + d] = (part[0][dl]+part[1][dl]+part[2][dl]+part[3][dl])*0.03125f;
}

// ---- final pool LN ----
__global__ __launch_bounds__(256) void k_poolB(const float* __restrict__ sraw,
   const float* __restrict__ g_aat, const float* __restrict__ be_aat, float* __restrict__ spool){
  int b = blockIdx.x; int tid = threadIdx.x;
  int d0 = tid*2;
  float2 a = *reinterpret_cast<const float2*>(&sraw[(size_t)b*512 + d0]);
  __shared__ float red[8];
  int wave=tid>>6,lane=tid&63;
  float s1 = a.x+a.y, s2 = a.x*a.x+a.y*a.y;
  float w1=waveSum(s1), w2=waveSum(s2);
  if(lane==0){red[wave]=w1; red[4+wave]=w2;}
  __syncthreads();
  s1=red[0]+red[1]+red[2]+red[3];
  s2=red[4]+red[5]+red[6]+red[7];
  float m=s1*(1.f/512.f), var=s2*(1.f/512.f)-m*m, rstd=rsqrtf(var+1e-5f);
  float2 ug=*reinterpret_cast<const float2*>(g_aat+d0);
  float2 ub=*reinterpret_cast<const float2*>(be_aat+d0);
  spool[(size_t)b*512+d0]   = (a.x-m)*rstd*ug.x+ub.x;
  spool[(size_t)b*512+d0+1] = (a.y-m)*rstd*ug.y+ub.y;
}

// ---- final head: P = sigmoid(cat(spool, ott) @ Wh + bh) ----
__global__ __launch_bounds__(256) void k_final(const float* __restrict__ spool, const float* __restrict__ vecst,
    const float* __restrict__ Wh, const float* __restrict__ bh, float* __restrict__ Pout){
  int b = blockIdx.x; int tid = threadIdx.x;
  float part = 0.f;
  for (int i = tid; i < 2560; i += 256){
    float v;
    if (i < 512) v = spool[(size_t)b*512 + i];
    else {
      int j = i - 512;
      v = vecst[(size_t)(j>>7)*(B_*SET_) + b*SET_ + (j&127)];
    }
    part += v * Wh[i];
  }
  __shared__ float red[4];
  int wave=tid>>6,lane=tid&63;
  float w = waveSum(part);
  if(lane==0) red[wave]=w;
  __syncthreads();
  if (tid==0){
    float x = red[0]+red[1]+red[2]+red[3] + bh[0];
    Pout[b] = 1.0f/(1.0f+expf(-x));
  }
}

extern "C" void kernel_launch(void* const* d_in, const int* in_sizes, int n_in,
                              void* d_out, int out_size, void* d_ws, size_t ws_size,
                              hipStream_t stream){
  const float* emb   = (const float*)d_in[0];
  const float* W_att = (const float*)d_in[1];
  const float* b_att = (const float*)d_in[2];
  const float* g_att = (const float*)d_in[3];
  const float* be_att= (const float*)d_in[4];
  const float* W_pro = (const float*)d_in[5];
  const float* b_pro = (const float*)d_in[6];
  const float* w_p1  = (const float*)d_in[7];
  const float* b_p1  = (const float*)d_in[8];
  const float* W_FI  = (const float*)d_in[9];
  const float* b_FI  = (const float*)d_in[10];
  const float* W_Set = (const float*)d_in[11];
  const float* b_Set = (const float*)d_in[12];
  const float* g_n   = (const float*)d_in[13];
  const float* be_n  = (const float*)d_in[14];
  const float* w_aat = (const float*)d_in[15];
  const float* b_aat = (const float*)d_in[16];
  const float* g_aat = (const float*)d_in[17];
  const float* be_aat= (const float*)d_in[18];
  const float* W_h2p = (const float*)d_in[19];
  const float* b_h2p = (const float*)d_in[20];
  float* out = (float*)d_out;

  float* ws = (float*)d_ws;
  float* temb  = ws;                      // 8,388,608
  float* att_t = temb + 8388608;          // 1,048,576  [B][K][L]
  float* spart = att_t + 1048576;         // 2,097,152
  float* fiin  = spart + 2097152;         // 8,192
  float* vecst = fiin + 8192;             // 131,072
  float* ratef = vecst + 131072;          // 16,384
  float* spool = ratef + 16384;           // 8,192
  float* res   = spool + 8192;            // 8,192
  float* sraw  = res + 8192;              // 8,192

  hipMemcpyAsync(temb, emb, (size_t)8388608*4, hipMemcpyDeviceToDevice, stream);
  for (int l=0; l<16; ++l){
    k_rate_gemm<<<512,256,0,stream>>>(temb, W_att + (size_t)l*32768, b_att + l*64, att_t);
    k_softmax_seq<<<1024,256,0,stream>>>(att_t);
    k_spart_gemm<<<dim3(8,4,16),256,0,stream>>>(temb, att_t, spart);
    k_sln_vec<<<1024,64,0,stream>>>(spart, g_att + (size_t)l*32768, be_att + (size_t)l*32768,
                                    W_pro + (size_t)l*262144, b_pro + l*512, fiin);
    k_fi<<<dim3(8,16),256,0,stream>>>(fiin, W_FI + (size_t)l*262144, b_FI + l*512, res);
    k_set<<<dim3(2,16),256,0,stream>>>(res, W_Set + (size_t)l*65536, b_Set + l*128,
                                       vecst + (size_t)l*2048);
    k_update<<<16384,256,0,stream>>>(temb, att_t, w_p1 + l*512, b_p1 + l*512,
                                     g_n + l*512, be_n + l*512, out + 16, l);
  }
  k_aat_rate<<<16384,64,0,stream>>>(temb, w_aat, b_aat, ratef);
  k_softmax_seq<<<16,256,0,stream>>>(ratef);
  k_poolA<<<dim3(8,16),256,0,stream>>>(temb, ratef, sraw);
  k_poolB<<<16,256,0,stream>>>(sraw, g_aat, be_aat, spool);
  k_final<<<16,256,0,stream>>>(spool, vecst, W_h2p, b_h2p, out);
}